// Round 7
// baseline (9288.721 us; speedup 1.0000x reference)
//
#include <hip/hip_runtime.h>
#include <cstdint>
#include <cstddef>

#define NDIM 8192
#define NITER 20
#define LDSN 8448   // 8192 + 8192/32 swizzle pad

typedef unsigned int uint4v __attribute__((ext_vector_type(4)));

// ---------- helpers ----------
__device__ __forceinline__ unsigned short f2bf_rne(float f) {
  unsigned int u = __float_as_uint(f);
  unsigned int r = 0x7fffu + ((u >> 16) & 1u);
  return (unsigned short)((u + r) >> 16);
}
__device__ __forceinline__ unsigned int pack2(float lo, float hi) {
  return (unsigned int)f2bf_rne(lo) | ((unsigned int)f2bf_rne(hi) << 16);
}
__device__ __forceinline__ float bflo(unsigned int u) { return __uint_as_float(u << 16); }
__device__ __forceinline__ float bfhi(unsigned int u) { return __uint_as_float(u & 0xffff0000u); }

// ---------- kernels ----------

// Iteration 1 fused with exp (proven R3 version): read H, write E=bf16(exp(H)),
// a = 1/rowsum (b==1), one partial row per 8-row block (1024 partial rows).
__global__ __launch_bounds__(1024) void k_first(const float* __restrict__ H,
                                                unsigned short* __restrict__ E,
                                                float* __restrict__ a,
                                                float* __restrict__ partial) {
  const int t = threadIdx.x;
  const int j0 = t * 8;
  const int i0 = blockIdx.x * 8;
  __shared__ float ash[8];

  uint4 cur[8];
  float dots[8];
#pragma unroll
  for (int r = 0; r < 8; ++r) {
    const float* hp = H + (size_t)(i0 + r) * NDIM + j0;
    float4 h0 = reinterpret_cast<const float4*>(hp)[0];
    float4 h1 = reinterpret_cast<const float4*>(hp)[1];
    float e0 = __expf(h0.x), e1 = __expf(h0.y), e2 = __expf(h0.z), e3 = __expf(h0.w);
    float e4 = __expf(h1.x), e5 = __expf(h1.y), e6 = __expf(h1.z), e7 = __expf(h1.w);
    cur[r] = uint4{pack2(e0, e1), pack2(e2, e3), pack2(e4, e5), pack2(e6, e7)};
    *reinterpret_cast<uint4*>(E + (size_t)(i0 + r) * NDIM + j0) = cur[r];
    dots[r] = ((e0 + e1) + (e2 + e3)) + ((e4 + e5) + (e6 + e7));
  }

  // block reduce (2 barriers)
#pragma unroll
  for (int r = 0; r < 8; ++r)
#pragma unroll
    for (int m = 32; m >= 1; m >>= 1)
      dots[r] += __shfl_xor(dots[r], m, 64);
  __shared__ float red[16][8];
  const int w = t >> 6;
  if ((t & 63) == 0) {
#pragma unroll
    for (int r = 0; r < 8; ++r) red[w][r] = dots[r];
  }
  __syncthreads();
  if (t < 8) {
    float s = 0.0f;
#pragma unroll
    for (int ww = 0; ww < 16; ++ww) s += red[ww][t];
    float inv = 1.0f / s;
    ash[t] = inv;
    a[i0 + t] = inv;
  }
  __syncthreads();

  float cs[8];
#pragma unroll
  for (int k = 0; k < 8; ++k) cs[k] = 0.0f;
#pragma unroll
  for (int r = 0; r < 8; ++r) {
    const float ai = ash[r];
    cs[0] += ai * bflo(cur[r].x); cs[1] += ai * bfhi(cur[r].x);
    cs[2] += ai * bflo(cur[r].y); cs[3] += ai * bfhi(cur[r].y);
    cs[4] += ai * bflo(cur[r].z); cs[5] += ai * bfhi(cur[r].z);
    cs[6] += ai * bflo(cur[r].w); cs[7] += ai * bfhi(cur[r].w);
  }
  float4* pp = reinterpret_cast<float4*>(partial + (size_t)blockIdx.x * NDIM + j0);
  pp[0] = float4{cs[0], cs[1], cs[2], cs[3]};
  pp[1] = float4{cs[4], cs[5], cs[6], cs[7]};
}

// Generic iteration, wave-autonomous: one wave owns one full row.
// 512 blocks x 512 threads (8 waves); block covers 16 rows, wave does 2.
// Row dot: in-wave shuffle reduce (NO barriers). Colsums: swizzled-LDS
// atomicAdd (2-way bank conflicts only). One partial row per block.
__global__ __launch_bounds__(512, 4) void k_iter(const unsigned short* __restrict__ E,
                                                 const float* __restrict__ b,
                                                 float* __restrict__ a,
                                                 float* __restrict__ partial) {
  __shared__ float cols[LDSN];
  const int t = threadIdx.x;
  const int lane = t & 63;
  const int w = t >> 6;                    // wave 0..7
  const int i0 = blockIdx.x * 16;

  for (int k = t; k < LDSN; k += 512) cols[k] = 0.0f;
  __syncthreads();

  const float4* b4 = reinterpret_cast<const float4*>(b);

#pragma unroll 1
  for (int rr = 0; rr < 2; ++rr) {
    const int row = i0 + w * 2 + rr;
    const unsigned short* rp = E + (size_t)row * NDIM;

    uint4v Ev[16];
#pragma unroll
    for (int c = 0; c < 16; ++c)
      Ev[c] = __builtin_nontemporal_load(
          reinterpret_cast<const uint4v*>(rp + (size_t)(c * 64 + lane) * 8));

    float dot = 0.0f;
#pragma unroll
    for (int c = 0; c < 16; ++c) {
      const float4 b0 = b4[(c * 64 + lane) * 2];
      const float4 b1 = b4[(c * 64 + lane) * 2 + 1];
      dot += ((bflo(Ev[c].x) * b0.x + bfhi(Ev[c].x) * b0.y) +
              (bflo(Ev[c].y) * b0.z + bfhi(Ev[c].y) * b0.w)) +
             ((bflo(Ev[c].z) * b1.x + bfhi(Ev[c].z) * b1.y) +
              (bflo(Ev[c].w) * b1.z + bfhi(Ev[c].w) * b1.w));
    }
#pragma unroll
    for (int m = 32; m >= 1; m >>= 1) dot += __shfl_xor(dot, m, 64);
    const float ai = 1.0f / dot;
    if (lane == 0) a[row] = ai;

#pragma unroll
    for (int c = 0; c < 16; ++c) {
      const int col0 = (c * 64 + lane) * 8;
      const int idx = col0 + (col0 >> 5);          // swizzle: 2-way banks
      atomicAdd(&cols[idx + 0], ai * bflo(Ev[c].x));
      atomicAdd(&cols[idx + 1], ai * bfhi(Ev[c].x));
      atomicAdd(&cols[idx + 2], ai * bflo(Ev[c].y));
      atomicAdd(&cols[idx + 3], ai * bfhi(Ev[c].y));
      atomicAdd(&cols[idx + 4], ai * bflo(Ev[c].z));
      atomicAdd(&cols[idx + 5], ai * bfhi(Ev[c].z));
      atomicAdd(&cols[idx + 6], ai * bflo(Ev[c].w));
      atomicAdd(&cols[idx + 7], ai * bfhi(Ev[c].w));
    }
  }
  __syncthreads();

  // de-swizzle dump: thread t owns cols [16t, 16t+16) (contiguous in LDS too)
  {
    const int col0 = t * 16;
    const int base = col0 + (col0 >> 5);
    float* pp = partial + (size_t)blockIdx.x * NDIM + col0;
#pragma unroll
    for (int k = 0; k < 16; ++k) pp[k] = cols[base + k];
  }
}

// b[j] = 1 / sum_{p<nrows} partial[p][j]
__global__ void k_colreduce(const float* __restrict__ partial, int nrows,
                            float* __restrict__ b) {
  const int j = blockIdx.x * blockDim.x + threadIdx.x;   // 32 blocks x 256 threads
  float s[8];
#pragma unroll
  for (int q = 0; q < 8; ++q) s[q] = 0.0f;
  for (int p = 0; p < nrows; p += 8) {
#pragma unroll
    for (int q = 0; q < 8; ++q)
      s[q] += partial[(size_t)(p + q) * NDIM + j];
  }
  b[j] = 1.0f / (((s[0] + s[1]) + (s[2] + s[3])) + ((s[4] + s[5]) + (s[6] + s[7])));
}

// out[i][j] = exp(H[i][j]) * a[i] * b[j]  (fp32; overwrites E/partial — dead)
__global__ void k_final(const float* __restrict__ H,
                        const float* __restrict__ a,
                        const float* __restrict__ b,
                        float* __restrict__ out) {
  const size_t nv = (size_t)NDIM * NDIM / 4;
  const size_t stride = (size_t)gridDim.x * blockDim.x;
  for (size_t v = (size_t)blockIdx.x * blockDim.x + threadIdx.x; v < nv; v += stride) {
    float4 h = reinterpret_cast<const float4*>(H)[v];
    const int i = (int)(v >> 11);
    const int jv = (int)(v & 2047);
    float4 bb = reinterpret_cast<const float4*>(b)[jv];
    const float ai = a[i];
    float4 o;
    o.x = __expf(h.x) * ai * bb.x;
    o.y = __expf(h.y) * ai * bb.y;
    o.z = __expf(h.z) * ai * bb.z;
    o.w = __expf(h.w) * ai * bb.w;
    reinterpret_cast<float4*>(out)[v] = o;
  }
}

// ---------- launch ----------
extern "C" void kernel_launch(void* const* d_in, const int* in_sizes, int n_in,
                              void* d_out, int out_size, void* d_ws, size_t ws_size,
                              hipStream_t stream) {
  const float* H = (const float*)d_in[0];
  float* out = (float*)d_out;
  unsigned short* E = (unsigned short*)d_out;                          // 128MB bf16
  float* partial = (float*)((char*)d_out + (size_t)NDIM * NDIM * 2);   // up to 32MB
  float* a = (float*)d_ws;                                             // [NDIM]
  float* b = a + NDIM;                                                 // [NDIM]

  // iteration 1 (b == 1), fused with exp; 1024 partial rows
  k_first<<<NDIM / 8, 1024, 0, stream>>>(H, E, a, partial);
  k_colreduce<<<NDIM / 256, 256, 0, stream>>>(partial, 1024, b);

  // iterations 2..20; wave-per-row, 512 partial rows
  for (int it = 1; it < NITER; ++it) {
    k_iter<<<NDIM / 16, 512, 0, stream>>>(E, b, a, partial);
    k_colreduce<<<NDIM / 256, 256, 0, stream>>>(partial, 512, b);
  }

  k_final<<<2048, 256, 0, stream>>>(H, a, b, out);
}

// Round 8
// 1506.384 us; speedup vs baseline: 6.1662x; 6.1662x over previous
//
#include <hip/hip_runtime.h>
#include <cstdint>
#include <cstddef>

#define NDIM 8192
#define NITER 20
#define TROWS 4                         // rows per LDS tile (64KB)
#define TILES 4                         // tiles per block -> 16 rows/block
#define GRID_ITER (NDIM / (TROWS * TILES))   // 512 blocks = 2 per CU

// ---------- helpers ----------
__device__ __forceinline__ unsigned short f2bf_rne(float f) {
  unsigned int u = __float_as_uint(f);
  unsigned int r = 0x7fffu + ((u >> 16) & 1u);
  return (unsigned short)((u + r) >> 16);
}
__device__ __forceinline__ unsigned int pack2(float lo, float hi) {
  return (unsigned int)f2bf_rne(lo) | ((unsigned int)f2bf_rne(hi) << 16);
}
__device__ __forceinline__ float bflo(unsigned int u) { return __uint_as_float(u << 16); }
__device__ __forceinline__ float bfhi(unsigned int u) { return __uint_as_float(u & 0xffff0000u); }

typedef __attribute__((address_space(1))) const unsigned int GA;
typedef __attribute__((address_space(3))) unsigned int LA;
// async global->LDS, 16B per lane; ldst must be wave-uniform base (HW adds lane*16)
__device__ __forceinline__ void gload16(const void* g, void* l) {
  __builtin_amdgcn_global_load_lds((GA*)g, (LA*)l, 16, 0, 0);
}

// ---------- kernels ----------

// Iteration 1 fused with exp (proven R3 version): read H, write E=bf16(exp(H)),
// a = 1/rowsum (b==1), one partial row per 8-row block (1024 partial rows).
__global__ __launch_bounds__(1024) void k_first(const float* __restrict__ H,
                                                unsigned short* __restrict__ E,
                                                float* __restrict__ a,
                                                float* __restrict__ partial) {
  const int t = threadIdx.x;
  const int j0 = t * 8;
  const int i0 = blockIdx.x * 8;
  __shared__ float ash[8];

  uint4 cur[8];
  float dots[8];
#pragma unroll
  for (int r = 0; r < 8; ++r) {
    const float* hp = H + (size_t)(i0 + r) * NDIM + j0;
    float4 h0 = reinterpret_cast<const float4*>(hp)[0];
    float4 h1 = reinterpret_cast<const float4*>(hp)[1];
    float e0 = __expf(h0.x), e1 = __expf(h0.y), e2 = __expf(h0.z), e3 = __expf(h0.w);
    float e4 = __expf(h1.x), e5 = __expf(h1.y), e6 = __expf(h1.z), e7 = __expf(h1.w);
    cur[r] = uint4{pack2(e0, e1), pack2(e2, e3), pack2(e4, e5), pack2(e6, e7)};
    *reinterpret_cast<uint4*>(E + (size_t)(i0 + r) * NDIM + j0) = cur[r];
    dots[r] = ((e0 + e1) + (e2 + e3)) + ((e4 + e5) + (e6 + e7));
  }

#pragma unroll
  for (int r = 0; r < 8; ++r)
#pragma unroll
    for (int m = 32; m >= 1; m >>= 1)
      dots[r] += __shfl_xor(dots[r], m, 64);
  __shared__ float red[16][8];
  const int w = t >> 6;
  if ((t & 63) == 0) {
#pragma unroll
    for (int r = 0; r < 8; ++r) red[w][r] = dots[r];
  }
  __syncthreads();
  if (t < 8) {
    float s = 0.0f;
#pragma unroll
    for (int ww = 0; ww < 16; ++ww) s += red[ww][t];
    float inv = 1.0f / s;
    ash[t] = inv;
    a[i0 + t] = inv;
  }
  __syncthreads();

  float cs[8];
#pragma unroll
  for (int k = 0; k < 8; ++k) cs[k] = 0.0f;
#pragma unroll
  for (int r = 0; r < 8; ++r) {
    const float ai = ash[r];
    cs[0] += ai * bflo(cur[r].x); cs[1] += ai * bfhi(cur[r].x);
    cs[2] += ai * bflo(cur[r].y); cs[3] += ai * bfhi(cur[r].y);
    cs[4] += ai * bflo(cur[r].z); cs[5] += ai * bfhi(cur[r].z);
    cs[6] += ai * bflo(cur[r].w); cs[7] += ai * bfhi(cur[r].w);
  }
  float4* pp = reinterpret_cast<float4*>(partial + (size_t)blockIdx.x * NDIM + j0);
  pp[0] = float4{cs[0], cs[1], cs[2], cs[3]};
  pp[1] = float4{cs[4], cs[5], cs[6], cs[7]};
}

// Generic iteration: LDS-staged one-pass. Block = 1024 threads, 4 tiles of
// 4 full rows (64KB LDS each, linear copy of 4 contiguous E rows via
// global_load_lds -> zero VGPR staging cost). Live regs ~45 < the 64-VGPR
// cap hipcc imposes on 1024-thread kernels. 2 blocks/CU co-resident.
__global__ __launch_bounds__(1024) void k_iter(const unsigned short* __restrict__ E,
                                               const float* __restrict__ b,
                                               float* __restrict__ a,
                                               float* __restrict__ partial) {
  __shared__ __align__(16) unsigned short tile[TROWS * NDIM];  // 64KB
  __shared__ float red[16];
  __shared__ float aish[TROWS];

  const int t = threadIdx.x;
  const int lane = t & 63;
  const int w = t >> 6;                 // wave 0..15
  const int blk = blockIdx.x;
  const int row_base = blk * (TROWS * TILES);

  float cs[8];
#pragma unroll
  for (int k = 0; k < 8; ++k) cs[k] = 0.0f;

#pragma unroll 1
  for (int tl = 0; tl < TILES; ++tl) {
    // ---- stage 4 rows (64KB): wave w copies 1KB segments w*4+k ----
    const char* src = (const char*)(E + (size_t)(row_base + tl * TROWS) * NDIM);
#pragma unroll
    for (int k = 0; k < 4; ++k) {
      const int seg = w * 4 + k;                       // 0..63
      gload16(src + seg * 1024 + lane * 16, (char*)tile + seg * 1024);
    }
    __syncthreads();   // barrier drains vmcnt(0): staged data visible

    // ---- dot phase: row r = t>>8 (256 threads/row), dwords ci+256k ----
    {
      const int r = t >> 8;
      const int ci = t & 255;
      const unsigned int* trow = (const unsigned int*)(tile + r * NDIM);
      float dot = 0.0f;
#pragma unroll
      for (int k = 0; k < 16; ++k) {
        const unsigned int u = trow[ci + 256 * k];
        const float2 bb = *(const float2*)(b + 2 * (ci + 256 * k));
        dot += bflo(u) * bb.x + bfhi(u) * bb.y;
      }
#pragma unroll
      for (int m = 32; m >= 1; m >>= 1) dot += __shfl_xor(dot, m, 64);
      if (lane == 0) red[w] = dot;
    }
    __syncthreads();
    if (t < TROWS) {
      const float s = ((red[4 * t] + red[4 * t + 1]) + (red[4 * t + 2] + red[4 * t + 3]));
      const float inv = 1.0f / s;
      a[row_base + tl * TROWS + t] = inv;
      aish[t] = inv;
    }
    __syncthreads();

    // ---- colacc: thread owns dwords t+1024k (8 cols), sums 4 rows ----
    {
      const float ai0 = aish[0], ai1 = aish[1], ai2 = aish[2], ai3 = aish[3];
      const unsigned int* tp = (const unsigned int*)tile;  // 4096 dwords/row
#pragma unroll
      for (int k = 0; k < 4; ++k) {
        const int d = t + 1024 * k;
        const unsigned int u0 = tp[0 * 4096 + d];
        const unsigned int u1 = tp[1 * 4096 + d];
        const unsigned int u2 = tp[2 * 4096 + d];
        const unsigned int u3 = tp[3 * 4096 + d];
        cs[2 * k]     += (ai0 * bflo(u0) + ai1 * bflo(u1)) + (ai2 * bflo(u2) + ai3 * bflo(u3));
        cs[2 * k + 1] += (ai0 * bfhi(u0) + ai1 * bfhi(u1)) + (ai2 * bfhi(u2) + ai3 * bfhi(u3));
      }
    }
    __syncthreads();   // tile fully consumed; safe to restage
  }

  // ---- one partial row per block ----
  float* pp = partial + (size_t)blk * NDIM;
#pragma unroll
  for (int k = 0; k < 4; ++k) {
    const int d = t + 1024 * k;
    *(float2*)(pp + 2 * d) = float2{cs[2 * k], cs[2 * k + 1]};
  }
}

// b[j] = 1 / sum_{p<nrows} partial[p][j]
__global__ void k_colreduce(const float* __restrict__ partial, int nrows,
                            float* __restrict__ b) {
  const int j = blockIdx.x * blockDim.x + threadIdx.x;   // 32 blocks x 256 threads
  float s[8];
#pragma unroll
  for (int q = 0; q < 8; ++q) s[q] = 0.0f;
  for (int p = 0; p < nrows; p += 8) {
#pragma unroll
    for (int q = 0; q < 8; ++q)
      s[q] += partial[(size_t)(p + q) * NDIM + j];
  }
  b[j] = 1.0f / (((s[0] + s[1]) + (s[2] + s[3])) + ((s[4] + s[5]) + (s[6] + s[7])));
}

// out[i][j] = exp(H[i][j]) * a[i] * b[j]  (fp32; overwrites E/partial — dead)
__global__ void k_final(const float* __restrict__ H,
                        const float* __restrict__ a,
                        const float* __restrict__ b,
                        float* __restrict__ out) {
  const size_t nv = (size_t)NDIM * NDIM / 4;
  const size_t stride = (size_t)gridDim.x * blockDim.x;
  for (size_t v = (size_t)blockIdx.x * blockDim.x + threadIdx.x; v < nv; v += stride) {
    float4 h = reinterpret_cast<const float4*>(H)[v];
    const int i = (int)(v >> 11);
    const int jv = (int)(v & 2047);
    float4 bb = reinterpret_cast<const float4*>(b)[jv];
    const float ai = a[i];
    float4 o;
    o.x = __expf(h.x) * ai * bb.x;
    o.y = __expf(h.y) * ai * bb.y;
    o.z = __expf(h.z) * ai * bb.z;
    o.w = __expf(h.w) * ai * bb.w;
    reinterpret_cast<float4*>(out)[v] = o;
  }
}

// ---------- launch ----------
extern "C" void kernel_launch(void* const* d_in, const int* in_sizes, int n_in,
                              void* d_out, int out_size, void* d_ws, size_t ws_size,
                              hipStream_t stream) {
  const float* H = (const float*)d_in[0];
  float* out = (float*)d_out;
  unsigned short* E = (unsigned short*)d_out;                          // 128MB bf16
  float* partial = (float*)((char*)d_out + (size_t)NDIM * NDIM * 2);   // up to 32MB
  float* a = (float*)d_ws;                                             // [NDIM]
  float* b = a + NDIM;                                                 // [NDIM]

  // iteration 1 (b == 1), fused with exp; 1024 partial rows
  k_first<<<NDIM / 8, 1024, 0, stream>>>(H, E, a, partial);
  k_colreduce<<<NDIM / 256, 256, 0, stream>>>(partial, 1024, b);

  // iterations 2..20; LDS-staged, 512 partial rows
  for (int it = 1; it < NITER; ++it) {
    k_iter<<<GRID_ITER, 1024, 0, stream>>>(E, b, a, partial);
    k_colreduce<<<NDIM / 256, 256, 0, stream>>>(partial, 512, b);
  }

  k_final<<<2048, 256, 0, stream>>>(H, a, b, out);
}